// Round 15
// baseline (127.681 us; speedup 1.0000x reference)
//
#include <hip/hip_runtime.h>
#include <hip/hip_bf16.h>

typedef __bf16 bf16x8 __attribute__((ext_vector_type(8)));
typedef __bf16 bf16x4 __attribute__((ext_vector_type(4)));
typedef float  f32x4  __attribute__((ext_vector_type(4)));

constexpr int NN = 16384;
constexpr int EE = 64;
constexpr int DD = 128;
constexpr int EG  = 8;     // experts per block

// ---------- pre-pass 1: X f32 -> bf16 row-major [N][D] ----------
__global__ __launch_bounds__(256)
void cvt_x(const float* __restrict__ X, __bf16* __restrict__ Xb) {
    int i = blockIdx.x * 256 + threadIdx.x;
    const float4* src = (const float4*)X;
    float4 v0 = src[2*i], v1 = src[2*i+1];
    bf16x8 p;
    p[0]=(__bf16)v0.x; p[1]=(__bf16)v0.y; p[2]=(__bf16)v0.z; p[3]=(__bf16)v0.w;
    p[4]=(__bf16)v1.x; p[5]=(__bf16)v1.y; p[6]=(__bf16)v1.z; p[7]=(__bf16)v1.w;
    ((bf16x8*)Xb)[i] = p;
}

// ---------- pre-pass 2: W[e][d][f] f32 -> per-expert SWIZZLED bf16 [f][d] ----------
// Element (f,d) at byte (f*256 + d*2) ^ ((f&7)<<4) within expert's 32KB.
// global_load_lds copies linearly; ds_read applies the same XOR (rule #21).
__global__ __launch_bounds__(256)
void cvt_wt(const float* __restrict__ W, __bf16* __restrict__ WTs) {
    __shared__ __bf16 T[DD][DD + 1];
    const int e = blockIdx.x;
    const int t = threadIdx.x;
    const float4* Wg = (const float4*)(W + (size_t)e * DD * DD);
    #pragma unroll
    for (int i = 0; i < 16; ++i) {
        int ft = i * 256 + t;
        int d = ft >> 5, f0 = (ft & 31) * 4;
        float4 v = Wg[ft];
        T[f0+0][d] = (__bf16)v.x;
        T[f0+1][d] = (__bf16)v.y;
        T[f0+2][d] = (__bf16)v.z;
        T[f0+3][d] = (__bf16)v.w;
    }
    __syncthreads();
    char* out = (char*)WTs + (size_t)e * DD * DD * 2;
    #pragma unroll
    for (int i = 0; i < 8; ++i) {
        int ft = i * 256 + t;
        int f = ft >> 4, d0 = (ft & 15) * 8;
        bf16x8 p;
        #pragma unroll
        for (int j = 0; j < 8; ++j) p[j] = T[f][d0 + j];
        int off = f * 256 + d0 * 2;
        off ^= (f & 7) << 4;
        *(bf16x8*)(out + off) = p;
    }
}

__device__ __forceinline__ void gll16(const void* g, void* l) {
    __builtin_amdgcn_global_load_lds(
        (const __attribute__((address_space(1))) void*)g,
        (__attribute__((address_space(3))) void*)l, 16, 0, 0);
}

// ---------- main GEMM: col-partition, 512 thr / 8 waves, counted barriers ----------
// Block = 128 rows x 8 experts. Wave w owns col-strip [w*16,w*16+16) for ALL
// 128 rows (a[8][4] per wave). vs R13 (isolated change): W ds_reads drop to
// 1x amplification (4 KB/wave/expert, was 16 KB); obuf exchange is cross-wave
// (full 64 KB obuf) with TWO NON-DRAINING barriers: bar1 = lgkmcnt(0) only
// (stores keep flying), bar2 = vmcnt(8)+lgkmcnt(0) (retires glls, keeps this
// iter's 8 stores in flight). Bias via LDS (R13's fix). Stores = 1 KB rows.
__global__ __launch_bounds__(512, 1)
void experts_gemm_cp(const __bf16* __restrict__ Xb,
                     const __bf16* __restrict__ WTs,
                     const float* __restrict__ Bias,
                     float* __restrict__ O)
{
    __shared__ __align__(16) char lds[2*32768 + 65536 + 4096]; // Wdbuf|obuf|bias
    char* obuf = lds + 65536;                  // shared 64 KB (128 rows x 512 B)
    char* blds = lds + 131072;                 // 8 experts x 512 B bias
    const int t    = threadIdx.x;
    const int lane = t & 63, w = t >> 6;       // w 0..7 = col strip
    const int l15  = lane & 15, kg = lane >> 4;
    const int eg   = blockIdx.x & (EE/EG - 1);
    const int n0   = (blockIdx.x >> 3) * 128;
    const int e0   = eg * EG;

    // X fragments: all 128 rows, k = kk*32+kg*8 (~128 VGPR)
    bf16x8 a[8][4];
    {
        const __bf16* Xp = Xb + (size_t)(n0 + l15) * DD + kg*8;
        #pragma unroll
        for (int m = 0; m < 8; ++m)
            #pragma unroll
            for (int kk = 0; kk < 4; ++kk)
                a[m][kk] = *(const bf16x8*)(Xp + m*16*DD + kk*32);
    }

    // bias for all EG experts -> LDS (lgkm-only consumption in the loop)
    if (t < 256) {
        f32x4 v = ((const f32x4*)(Bias + e0*DD))[t];
        *(f32x4*)(blds + t*16) = v;
    }

    // prologue: stage W[e0] (full 32 KB; 4 KB per wave via 4 glls)
    {
        const char* src = (const char*)WTs + (size_t)e0 * 32768 + w*4096 + lane*16;
        char* dst = lds + w*4096;
        #pragma unroll
        for (int i = 0; i < 4; ++i) gll16(src + i*1024, dst + i*1024);
    }
    __syncthreads();   // one full drain; buf0 + bias ready

    int cur = 0;
    for (int ei = 0; ei < EG; ++ei) {
        const int e = e0 + ei;

        // prefetch next expert's W (stays in flight through compute)
        if (ei + 1 < EG) {
            const char* src = (const char*)WTs + (size_t)(e+1) * 32768 + w*4096 + lane*16;
            char* dst = lds + (cur ^ 1) * 32768 + w*4096;
            #pragma unroll
            for (int i = 0; i < 4; ++i) gll16(src + i*1024, dst + i*1024);
        }

        // bias via LDS: lane cols = w*16 + kg*4 .. +3
        f32x4 bv = *(const f32x4*)(blds + ei*512 + w*64 + kg*16);
        f32x4 acc[8];
        #pragma unroll
        for (int m = 0; m < 8; ++m) acc[m] = bv;

        // compute: 1 W-strip ds_read per kk (4 KB/expert total), 32 MFMA
        const char* buf = lds + cur * 32768;
        #pragma unroll
        for (int kk = 0; kk < 4; ++kk) {
            int off = (w*16 + l15)*256 + (kk*32 + kg*8)*2;
            off ^= (l15 & 7) << 4;
            bf16x8 b = *(const bf16x8*)(buf + off);
            #pragma unroll
            for (int m = 0; m < 8; ++m)
                acc[m] = __builtin_amdgcn_mfma_f32_16x16x32_bf16(
                    b, a[m][kk], acc[m], 0, 0, 0);
        }

        // obuf stage: row = m*16+l15 (0..127), strip bytes w*64 + kg*16
        #pragma unroll
        for (int m = 0; m < 8; ++m) {
            int row = m*16 + l15;
            int off = row*512 + w*64 + kg*16;
            off ^= (row & 7) << 4;
            *(f32x4*)(obuf + off) = acc[m];
        }

        // bar1: LDS-visibility only — NO vmcnt (stores keep draining)
        __builtin_amdgcn_sched_barrier(0);
        asm volatile("s_waitcnt lgkmcnt(0)" ::: "memory");
        __builtin_amdgcn_s_barrier();
        __builtin_amdgcn_sched_barrier(0);

        // readback + store: wave owns rows w*16..+15; per inst 2 FULL rows
        // (lanes 0-31 row r, 32-63 row r+1) = 1 KB contiguous.
        {
            const int c32 = lane & 31, rh = lane >> 5;
            #pragma unroll
            for (int i = 0; i < 8; ++i) {
                int row = w*16 + i*2 + rh;
                int off = row*512 + c32*16;
                off ^= (row & 7) << 4;
                f32x4 v = *(const f32x4*)(obuf + off);
                *(f32x4*)(O + (size_t)(n0 + row) * (EE*DD) + e*DD + c32*4) = v;
            }
        }

        // bar2: retire the 4 glls (+ prev iter's long-draining stores); keep
        // this iter's 8 stores (newest) in flight; obuf free for next iter.
        if (ei + 1 < EG) {
            __builtin_amdgcn_sched_barrier(0);
            asm volatile("s_waitcnt vmcnt(8) lgkmcnt(0)" ::: "memory");
            __builtin_amdgcn_s_barrier();
            __builtin_amdgcn_sched_barrier(0);
        }
        cur ^= 1;
    }
}

// ---------- fallback (round-0 kernel, used if ws too small) ----------
__global__ __launch_bounds__(256, 2)
void experts_gemm_fb(const float* __restrict__ X,
                     const float* __restrict__ W,
                     const float* __restrict__ Bias,
                     float* __restrict__ O)
{
    constexpr int BM = 128;
    __shared__ __align__(16) char lds[BM*DD*2 + DD*DD*2];
    __bf16* As = (__bf16*)lds;
    __bf16* Bs = (__bf16*)(lds + BM*DD*2);

    const int t   = threadIdx.x;
    const int e   = blockIdx.x & (EE - 1);
    const int n0  = (blockIdx.x >> 6) * BM;

    {
        const float4* Xg = (const float4*)(X + (size_t)n0 * DD);
        #pragma unroll
        for (int i = 0; i < 16; ++i) {
            int ft = i * 256 + t;
            float4 v = Xg[ft];
            int n = ft >> 5, d0 = (ft & 31) << 2;
            bf16x4 p;
            p[0]=(__bf16)v.x; p[1]=(__bf16)v.y; p[2]=(__bf16)v.z; p[3]=(__bf16)v.w;
            int off = n * 256 + d0 * 2;
            off ^= (n & 7) << 4;
            *(bf16x4*)((char*)As + off) = p;
        }
    }
    {
        const float4* Wg = (const float4*)(W + (size_t)e * DD * DD);
        #pragma unroll
        for (int i = 0; i < 4; ++i) {
            int bb = i * 256 + t;
            int db = bb >> 5, fb = bb & 31;
            float4 r0 = Wg[(db*4+0)*32 + fb];
            float4 r1 = Wg[(db*4+1)*32 + fb];
            float4 r2 = Wg[(db*4+2)*32 + fb];
            float4 r3 = Wg[(db*4+3)*32 + fb];
            const float* q0=(const float*)&r0; const float* q1=(const float*)&r1;
            const float* q2=(const float*)&r2; const float* q3=(const float*)&r3;
            #pragma unroll
            for (int j = 0; j < 4; ++j) {
                bf16x4 p;
                p[0]=(__bf16)q0[j]; p[1]=(__bf16)q1[j];
                p[2]=(__bf16)q2[j]; p[3]=(__bf16)q3[j];
                int f = fb * 4 + j;
                int off = f * 256 + db * 8;
                off ^= (f & 7) << 4;
                *(bf16x4*)((char*)Bs + off) = p;
            }
        }
    }
    __syncthreads();

    const int lane = t & 63, w = t >> 6;
    const int wr = w >> 1, wc = w & 1;
    const int l15 = lane & 15, kg = lane >> 4;

    f32x4 acc[4][4];
    #pragma unroll
    for (int m = 0; m < 4; ++m)
        #pragma unroll
        for (int n = 0; n < 4; ++n) {
            acc[m][n][0]=0.f; acc[m][n][1]=0.f; acc[m][n][2]=0.f; acc[m][n][3]=0.f;
        }

    float bias[4];
    #pragma unroll
    for (int n = 0; n < 4; ++n) bias[n] = Bias[e*DD + wc*64 + n*16 + l15];

    #pragma unroll
    for (int kk = 0; kk < 4; ++kk) {
        int koff = kk * 32 + kg * 8;
        bf16x8 av[4], bvv[4];
        #pragma unroll
        for (int m = 0; m < 4; ++m) {
            int row = wr*64 + m*16 + l15;
            int off = row * 256 + koff * 2;
            off ^= (row & 7) << 4;
            av[m] = *(const bf16x8*)((const char*)As + off);
        }
        #pragma unroll
        for (int n = 0; n < 4; ++n) {
            int col = wc*64 + n*16 + l15;
            int off = col * 256 + koff * 2;
            off ^= (col & 7) << 4;
            bvv[n] = *(const bf16x8*)((const char*)Bs + off);
        }
        #pragma unroll
        for (int m = 0; m < 4; ++m)
            #pragma unroll
            for (int n = 0; n < 4; ++n)
                acc[m][n] = __builtin_amdgcn_mfma_f32_16x16x32_bf16(
                    av[m], bvv[n], acc[m][n], 0, 0, 0);
    }

    float* Op = O + (size_t)n0 * (EE*DD) + (size_t)e * DD;
    #pragma unroll
    for (int m = 0; m < 4; ++m)
        #pragma unroll
        for (int n = 0; n < 4; ++n) {
            int cg = wc*64 + n*16 + l15;
            #pragma unroll
            for (int r = 0; r < 4; ++r) {
                int rg = wr*64 + m*16 + kg*4 + r;
                Op[(size_t)rg * (EE*DD) + cg] = acc[m][n][r] + bias[n];
            }
        }
}

extern "C" void kernel_launch(void* const* d_in, const int* in_sizes, int n_in,
                              void* d_out, int out_size, void* d_ws, size_t ws_size,
                              hipStream_t stream) {
    const float* X = (const float*)d_in[0];
    const float* W = (const float*)d_in[1];
    const float* B = (const float*)d_in[2];
    float* O = (float*)d_out;

    const size_t xb_bytes = (size_t)NN * DD * sizeof(__bf16);      // 4 MiB
    const size_t wt_bytes = (size_t)EE * DD * DD * sizeof(__bf16); // 2 MiB

    if (ws_size >= xb_bytes + wt_bytes) {
        __bf16* Xb  = (__bf16*)d_ws;
        __bf16* WTs = (__bf16*)((char*)d_ws + xb_bytes);
        cvt_x<<<NN * DD / 8 / 256, 256, 0, stream>>>(X, Xb);
        cvt_wt<<<EE, 256, 0, stream>>>(W, WTs);
        experts_gemm_cp<<<(NN / 128) * (EE / EG), 512, 0, stream>>>(Xb, WTs, B, O);
    } else {
        experts_gemm_fb<<<(NN / 128) * EE, 256, 0, stream>>>(X, W, B, O);
    }
}